// Round 14
// baseline (1055.660 us; speedup 1.0000x reference)
//
#include <hip/hip_runtime.h>
#include <cstdint>
#include <cstddef>

namespace {

constexpr int kNB   = 8;
constexpr int kN    = 4096;
constexpr int kS    = 1024;   // NPOINT
constexpr int kK    = 32;     // NSAMPLE
constexpr int kInCh = 64;
constexpr int kC0   = 67;     // 3 + 64
constexpr int kC0P  = 68;     // padded (zero col at c'=3)
constexpr int kC1   = 64;
constexpr int kC3   = 128;
constexpr int kRows = kNB * kS * kK;  // 262144
constexpr int kTileR = 128;
constexpr int kGemmBlocks = kRows / kTileR;  // 2048

typedef float v2f __attribute__((ext_vector_type(2)));

// DPP max step: invalid source lanes fall back to `old` = x (identity for max).
template <int CTRL>
__device__ __forceinline__ float dpp_max(float x) {
  const int o = __builtin_amdgcn_update_dpp(
      __float_as_int(x), __float_as_int(x), CTRL, 0xf, 0xf, false);
  const float of = __int_as_float(o);
  return of > x ? of : x;
}

// ---------------- Farthest point sampling -----------------------------------
// Wave-count curve on the lean structure: 16w/4pt = 0.73us/step (r9),
// 8w/8pt = 0.66 (r12). r13 completes the curve: 4 waves x 16 pts/lane
// (1 wave/SIMD -> zero intra-CU issue contention; barrier(4); 4 partials).
//  - one barrier/step; parity slots red[j&1][wid] WAR-safe.
//  - wave max via DPP row_shr/bcast + readlane(63); owner via ballot+ctz.
//  - red[p][wid] = u64 {value_bits:32, idx:32}; cross-wave: lane reads
//    red[p][lane&3], DPP row_shr 1/2 + readlane(3), ballot -> first lane
//    (<4) == first wave == min global index; index via readlane (SALU).
//  - centroid fetch: one uniform b128 broadcast sp[fi].
// Contiguous map i = 16*tid + t: min tie (t, lane, wave) == min global index
// == numpy first-occurrence argmax. Distance arithmetic bit-identical to
// numpy: ((dx*dx+dy*dy)+dz*dz), RN ops, no FMA (packed v2f, contract off).
__global__ __launch_bounds__(256, 1) void fps_kernel(const float* __restrict__ xyz,
                                                     float* __restrict__ newxyz) {
  __shared__ float4 sp[kN];                     // 64 KiB
  __shared__ unsigned long long red[2][4];
  const int tid = threadIdx.x;
  const int b = blockIdx.x;
  const float* xb = xyz + (size_t)b * kN * 3;
  for (int i = tid; i < kN; i += 256) {
    sp[i] = make_float4(xb[i * 3 + 0], xb[i * 3 + 1], xb[i * 3 + 2], 0.0f);
  }
  __syncthreads();
  const int i0 = tid * 16;
  v2f pxv[8], pyv[8], pzv[8], dv[8];
#pragma unroll
  for (int h = 0; h < 8; ++h) {
    const float4 p0 = sp[i0 + 2 * h + 0];
    const float4 p1 = sp[i0 + 2 * h + 1];
    pxv[h] = (v2f){p0.x, p1.x};
    pyv[h] = (v2f){p0.y, p1.y};
    pzv[h] = (v2f){p0.z, p1.z};
    dv[h]  = (v2f){1e10f, 1e10f};
  }
  float4 c4 = sp[0];
  float cx = c4.x, cy = c4.y, cz = c4.z;
  float* ob = newxyz + (size_t)b * kS * 3;
  if (tid == 0) { ob[0] = cx; ob[1] = cy; ob[2] = cz; }
  const int lane = tid & 63;
  const int wid  = tid >> 6;
  for (int j = 1; j < kS; ++j) {
    // Packed distance update (RN, no FMA; per-element order identical to numpy).
    const float ncx = -cx, ncy = -cy, ncz = -cz;
    const v2f cxv = (v2f){ncx, ncx}, cyv = (v2f){ncy, ncy}, czv = (v2f){ncz, ncz};
#pragma unroll
    for (int h = 0; h < 8; ++h) {
#pragma clang fp contract(off)
      const v2f dx = pxv[h] + cxv;
      const v2f dy = pyv[h] + cyv;
      const v2f dz = pzv[h] + czv;
      const v2f d0 = ((dx * dx + dy * dy) + dz * dz);
      dv[h] = __builtin_elementwise_min(dv[h], d0);
    }
    // First-max over 16 via adjacent-pairing tree (left range < right range at
    // every level, so strict '>' keeps the first occurrence exactly).
    float lv[8]; int lt[8];
#pragma unroll
    for (int h = 0; h < 8; ++h) {
      const bool g = dv[h].y > dv[h].x;
      lv[h] = g ? dv[h].y : dv[h].x;
      lt[h] = 2 * h + (g ? 1 : 0);
    }
    float qv[4]; int qt[4];
#pragma unroll
    for (int h = 0; h < 4; ++h) {
      const bool g = lv[2 * h + 1] > lv[2 * h];
      qv[h] = g ? lv[2 * h + 1] : lv[2 * h];
      qt[h] = g ? lt[2 * h + 1] : lt[2 * h];
    }
    const bool g01 = qv[1] > qv[0];
    const float v01 = g01 ? qv[1] : qv[0];
    const int   t01 = g01 ? qt[1] : qt[0];
    const bool g23 = qv[3] > qv[2];
    const float v23 = g23 ? qv[3] : qv[2];
    const int   t23 = g23 ? qt[3] : qt[2];
    const bool gf = v23 > v01;
    const float bv = gf ? v23 : v01;
    const int   bt = gf ? t23 : t01;
    // Wave max via DPP (pure VALU), broadcast from lane 63.
    float m = bv;
    m = dpp_max<0x111>(m);   // row_shr:1
    m = dpp_max<0x112>(m);   // row_shr:2
    m = dpp_max<0x114>(m);   // row_shr:4
    m = dpp_max<0x118>(m);   // row_shr:8
    m = dpp_max<0x142>(m);   // row_bcast:15
    m = dpp_max<0x143>(m);   // row_bcast:31
    const float mv = __int_as_float(__builtin_amdgcn_readlane(__float_as_int(m), 63));
    // First-occurrence: min tie lane == min global index (i = 16*tid + t).
    const unsigned long long msk = __ballot(bv == mv);
    const int owner = (int)__builtin_ctzll(msk);
    const int bto = __builtin_amdgcn_readlane(bt, owner);
    const int bidx = (wid * 64 + owner) * 16 + bto;
    const int p = j & 1;
    if (lane == 0) {
      red[p][wid] = ((unsigned long long)(unsigned int)__float_as_int(mv) << 32) |
                    (unsigned int)bidx;
    }
    __syncthreads();   // the ONLY barrier per step (parity slots are WAR-safe)
    // Cross-wave: one ds_read_b64 of red[p][lane&3]; DPP-max on the value (hi)
    // word over lanes 0..3; index via readlane from the first tying lane.
    const unsigned long long k64 = red[p][lane & 3];
    const float v2 = __int_as_float((int)(k64 >> 32));
    const int   li = (int)(unsigned int)(k64 & 0xffffffffull);
    float m2 = v2;
    m2 = dpp_max<0x111>(m2);
    m2 = dpp_max<0x112>(m2);
    const float mv2 = __int_as_float(__builtin_amdgcn_readlane(__float_as_int(m2), 3));
    const unsigned long long msk2 = __ballot(v2 == mv2);
    const int ow = (int)__builtin_ctzll(msk2);   // first lane (<4) == first wave
    const int fi = __builtin_amdgcn_readlane(li, ow);
    c4 = sp[fi];                                 // one b128 broadcast read
    cx = c4.x; cy = c4.y; cz = c4.z;
    if (tid == 0) { ob[j * 3 + 0] = cx; ob[j * 3 + 1] = cy; ob[j * 3 + 2] = cz; }
  }
}

// ---------------- Ball query -------------------------------------------------
// One wave per query point; first-32 in-radius indices in ascending order,
// padded with the first index. Distance uses the reference's expanded form and
// the compare is done in double (python float radius*radius).
__global__ __launch_bounds__(256) void ballq_kernel(const float* __restrict__ xyz,
                                                    const float* __restrict__ newxyz,
                                                    int* __restrict__ gidx) {
  const int tid  = threadIdx.x;
  const int lane = tid & 63;
  const int gq   = blockIdx.x * 4 + (tid >> 6);
  const int b    = gq >> 10;
  const float* xb = xyz + (size_t)b * kN * 3;
  const float qx = newxyz[gq * 3 + 0];
  const float qy = newxyz[gq * 3 + 1];
  const float qz = newxyz[gq * 3 + 2];
  const float s2 = __fadd_rn(__fadd_rn(__fmul_rn(qx, qx), __fmul_rn(qy, qy)),
                             __fmul_rn(qz, qz));
  const double r2 = 0.2 * 0.2;
  int taken = 0;
  int first = 0;
  bool hasfirst = false;
  int* g = gidx + (size_t)gq * kK;
  for (int base = 0; base < kN; base += 64) {
    const int n = base + lane;
    const float fx = xb[n * 3 + 0], fy = xb[n * 3 + 1], fz = xb[n * 3 + 2];
    const float p2 = __fadd_rn(__fadd_rn(__fmul_rn(fx, fx), __fmul_rn(fy, fy)),
                               __fmul_rn(fz, fz));
    const float dt = __fadd_rn(__fadd_rn(__fmul_rn(qx, fx), __fmul_rn(qy, fy)),
                               __fmul_rn(qz, fz));
    const float d = __fadd_rn(__fadd_rn(__fmul_rn(-2.0f, dt), s2), p2);
    const bool in = !((double)d > r2);
    const unsigned long long m = __ballot(in);
    if (!hasfirst && m != 0ull) { first = base + __builtin_ctzll(m); hasfirst = true; }
    if (in) {
      const int pos = taken + (int)__popcll(m & ((1ull << lane) - 1ull));
      if (pos < kK) g[pos] = n;
    }
    taken += (int)__popcll(m);
    if (taken >= kK) break;
  }
  for (int p = taken + lane; p < kK; p += 64) g[p] = first;
}

// ---------------- GEMM core (shared pattern) ---------------------------------
// Block: 256 threads, tile 128 rows x 64 cols. Thread (tr = tid&15, tc = tid>>4)
// computes rows {tr+16i} x cols {tc*4+j}, acc[8][4].

template <int KDIM>
__device__ __forceinline__ void gemm_compute(const float xs[kTileR][kC0P],
                                             const float wl[kC1][kC0P],
                                             int tr, int tc, float acc[8][4]) {
#pragma unroll
  for (int i = 0; i < 8; ++i)
#pragma unroll
    for (int j = 0; j < 4; ++j) acc[i][j] = 0.0f;
#pragma unroll 4
  for (int c = 0; c < KDIM; c += 4) {
    const float4 wv0 = *(const float4*)&wl[tc * 4 + 0][c];
    const float4 wv1 = *(const float4*)&wl[tc * 4 + 1][c];
    const float4 wv2 = *(const float4*)&wl[tc * 4 + 2][c];
    const float4 wv3 = *(const float4*)&wl[tc * 4 + 3][c];
#pragma unroll
    for (int i = 0; i < 8; ++i) {
      const float4 xv = *(const float4*)&xs[tr + 16 * i][c];
      acc[i][0] = fmaf(xv.x, wv0.x, acc[i][0]);
      acc[i][0] = fmaf(xv.y, wv0.y, acc[i][0]);
      acc[i][0] = fmaf(xv.z, wv0.z, acc[i][0]);
      acc[i][0] = fmaf(xv.w, wv0.w, acc[i][0]);
      acc[i][1] = fmaf(xv.x, wv1.x, acc[i][1]);
      acc[i][1] = fmaf(xv.y, wv1.y, acc[i][1]);
      acc[i][1] = fmaf(xv.z, wv1.z, acc[i][1]);
      acc[i][1] = fmaf(xv.w, wv1.w, acc[i][1]);
      acc[i][2] = fmaf(xv.x, wv2.x, acc[i][2]);
      acc[i][2] = fmaf(xv.y, wv2.y, acc[i][2]);
      acc[i][2] = fmaf(xv.z, wv2.z, acc[i][2]);
      acc[i][2] = fmaf(xv.w, wv2.w, acc[i][2]);
      acc[i][3] = fmaf(xv.x, wv3.x, acc[i][3]);
      acc[i][3] = fmaf(xv.y, wv3.y, acc[i][3]);
      acc[i][3] = fmaf(xv.z, wv3.z, acc[i][3]);
      acc[i][3] = fmaf(xv.w, wv3.w, acc[i][3]);
    }
  }
}

// Epilogue: add bias, write y, and per-channel {sum, sumsq} partials.
__device__ __forceinline__ void gemm_store_stats(float acc[8][4], const float* __restrict__ bias,
                                                 float* __restrict__ y,
                                                 float* __restrict__ psum, float* __restrict__ psq,
                                                 int R0, int tr, int tc, int bid) {
  float bb[4];
#pragma unroll
  for (int j = 0; j < 4; ++j) bb[j] = bias[tc * 4 + j];
  float sum[4] = {0, 0, 0, 0}, sq[4] = {0, 0, 0, 0};
#pragma unroll
  for (int i = 0; i < 8; ++i) {
    float v[4];
#pragma unroll
    for (int j = 0; j < 4; ++j) {
      const float t = acc[i][j] + bb[j];
      v[j] = t;
      sum[j] += t;
      sq[j] = fmaf(t, t, sq[j]);
    }
    *(float4*)&y[((size_t)(R0 + tr + 16 * i)) * kC1 + tc * 4] =
        make_float4(v[0], v[1], v[2], v[3]);
  }
#pragma unroll
  for (int off = 1; off < 16; off <<= 1) {
#pragma unroll
    for (int j = 0; j < 4; ++j) {
      sum[j] += __shfl_xor(sum[j], off, 64);
      sq[j]  += __shfl_xor(sq[j], off, 64);
    }
  }
  if (tr == 0) {
    *(float4*)&psum[(size_t)bid * kC1 + tc * 4] = make_float4(sum[0], sum[1], sum[2], sum[3]);
    *(float4*)&psq[(size_t)bid * kC1 + tc * 4]  = make_float4(sq[0], sq[1], sq[2], sq[3]);
  }
}

// ---------------- Layer 1: fused gather + GEMM(K=67->68, N=64) ---------------
__global__ __launch_bounds__(256) void gemm1_kernel(
    const float* __restrict__ xyz, const float* __restrict__ points,
    const float* __restrict__ newxyz, const int* __restrict__ gidx,
    const float* __restrict__ W, const float* __restrict__ bias,
    float* __restrict__ y, float* __restrict__ psum, float* __restrict__ psq) {
  __shared__ float xs[kTileR][kC0P];
  __shared__ float wl[kC1][kC0P];
  __shared__ int   gl[kTileR];
  __shared__ float nx[4][3];
  const int tid = threadIdx.x;
  const int R0  = blockIdx.x * kTileR;
  const int b   = R0 >> 15;          // 32768 rows per batch
  const int G0  = R0 >> 5;           // global group id base (4 groups per tile)
  if (tid < kTileR) gl[tid] = gidx[R0 + tid];
  if (tid >= 128 && tid < 140) {
    const int q = (tid - 128) / 3, c = (tid - 128) % 3;
    nx[q][c] = newxyz[(size_t)(G0 + q) * 3 + c];
  }
  // Stage W reordered: c'=0..2 -> W[:,0..2], c'=3 -> 0, c'>=4 -> W[:,c'-1]
  for (int i = tid; i < kC1 * kC0P; i += 256) {
    const int o = i / kC0P, c = i % kC0P;
    float v;
    if (c < 3)       v = W[o * kC0 + c];
    else if (c == 3) v = 0.0f;
    else             v = W[o * kC0 + (c - 1)];
    wl[o][c] = v;
  }
  __syncthreads();
  // Gather-stage xs: [dx,dy,dz,0, p0..p63]
  for (int i = tid; i < kTileR * 17; i += 256) {
    const int r = i / 17, q = i % 17;
    const int n = gl[r];
    if (q == 0) {
      const float* xp = xyz + ((size_t)(b * kN + n)) * 3;
      const int sq4 = r >> 5;
      xs[r][0] = __fsub_rn(xp[0], nx[sq4][0]);
      xs[r][1] = __fsub_rn(xp[1], nx[sq4][1]);
      xs[r][2] = __fsub_rn(xp[2], nx[sq4][2]);
      xs[r][3] = 0.0f;
    } else {
      const float4 p = *(const float4*)(points + ((size_t)(b * kN + n)) * kInCh + (q - 1) * 4);
      *(float4*)&xs[r][q * 4] = p;
    }
  }
  __syncthreads();
  const int tr = tid & 15, tc = tid >> 4;
  float acc[8][4];
  gemm_compute<kC0P>(xs, wl, tr, tc, acc);
  gemm_store_stats(acc, bias, y, psum, psq, R0, tr, tc, blockIdx.x);
}

// ---------------- Layer 2: GEMM(K=64, N=64), BN1+ReLU fused on input --------
__global__ __launch_bounds__(256) void gemm2_kernel(
    const float* __restrict__ x, const float* __restrict__ W, const float* __restrict__ bias,
    const float* __restrict__ a, const float* __restrict__ sft,
    float* __restrict__ y, float* __restrict__ psum, float* __restrict__ psq) {
  __shared__ float xs[kTileR][kC0P];
  __shared__ float wl[kC1][kC0P];
  const int tid = threadIdx.x;
  const int R0  = blockIdx.x * kTileR;
  for (int i = tid; i < kTileR * 16; i += 256) {
    const int r = i >> 4, cq = i & 15;
    float4 v = *(const float4*)&x[((size_t)(R0 + r)) * kC1 + cq * 4];
    const float4 av = *(const float4*)&a[cq * 4];
    const float4 sv = *(const float4*)&sft[cq * 4];
    v.x = fmaxf(fmaf(av.x, v.x, sv.x), 0.0f);
    v.y = fmaxf(fmaf(av.y, v.y, sv.y), 0.0f);
    v.z = fmaxf(fmaf(av.z, v.z, sv.z), 0.0f);
    v.w = fmaxf(fmaf(av.w, v.w, sv.w), 0.0f);
    *(float4*)&xs[r][cq * 4] = v;
  }
  for (int i = tid; i < kC1 * 16; i += 256) {
    const int o = i >> 4, cq = i & 15;
    *(float4*)&wl[o][cq * 4] = *(const float4*)&W[(size_t)o * kC1 + cq * 4];
  }
  __syncthreads();
  const int tr = tid & 15, tc = tid >> 4;
  float acc[8][4];
  gemm_compute<kC1>(xs, wl, tr, tc, acc);
  gemm_store_stats(acc, bias, y, psum, psq, R0, tr, tc, blockIdx.x);
}

// ---------------- Layer 3 pass A: stats only (no y3 store) -------------------
__global__ __launch_bounds__(256) void gemm3a_kernel(
    const float* __restrict__ x, const float* __restrict__ W, const float* __restrict__ bias,
    const float* __restrict__ a, const float* __restrict__ sft,
    float* __restrict__ psum, float* __restrict__ psq) {
  __shared__ float xs[kTileR][kC0P];
  __shared__ float wl[kC1][kC0P];
  const int tid = threadIdx.x;
  const int R0  = blockIdx.x * kTileR;
  for (int i = tid; i < kTileR * 16; i += 256) {
    const int r = i >> 4, cq = i & 15;
    float4 v = *(const float4*)&x[((size_t)(R0 + r)) * kC1 + cq * 4];
    const float4 av = *(const float4*)&a[cq * 4];
    const float4 sv = *(const float4*)&sft[cq * 4];
    v.x = fmaxf(fmaf(av.x, v.x, sv.x), 0.0f);
    v.y = fmaxf(fmaf(av.y, v.y, sv.y), 0.0f);
    v.z = fmaxf(fmaf(av.z, v.z, sv.z), 0.0f);
    v.w = fmaxf(fmaf(av.w, v.w, sv.w), 0.0f);
    *(float4*)&xs[r][cq * 4] = v;
  }
  const int tr = tid & 15, tc = tid >> 4;
  for (int cp = 0; cp < 2; ++cp) {
    __syncthreads();
    for (int i = tid; i < kC1 * 16; i += 256) {
      const int o = i >> 4, cq = i & 15;
      *(float4*)&wl[o][cq * 4] = *(const float4*)&W[((size_t)(cp * 64 + o)) * kC1 + cq * 4];
    }
    __syncthreads();
    float acc[8][4];
    gemm_compute<kC1>(xs, wl, tr, tc, acc);
    float bb[4];
#pragma unroll
    for (int j = 0; j < 4; ++j) bb[j] = bias[cp * 64 + tc * 4 + j];
    float sum[4] = {0, 0, 0, 0}, sq[4] = {0, 0, 0, 0};
#pragma unroll
    for (int i = 0; i < 8; ++i)
#pragma unroll
      for (int j = 0; j < 4; ++j) {
        const float t = acc[i][j] + bb[j];
        sum[j] += t;
        sq[j] = fmaf(t, t, sq[j]);
      }
#pragma unroll
    for (int off = 1; off < 16; off <<= 1) {
#pragma unroll
      for (int j = 0; j < 4; ++j) {
        sum[j] += __shfl_xor(sum[j], off, 64);
        sq[j]  += __shfl_xor(sq[j], off, 64);
      }
    }
    if (tr == 0) {
      *(float4*)&psum[(size_t)blockIdx.x * kC3 + cp * 64 + tc * 4] =
          make_float4(sum[0], sum[1], sum[2], sum[3]);
      *(float4*)&psq[(size_t)blockIdx.x * kC3 + cp * 64 + tc * 4] =
          make_float4(sq[0], sq[1], sq[2], sq[3]);
    }
  }
}

// ---------------- Layer 3 pass B: recompute + BN3 + ReLU + max over k -------
__global__ __launch_bounds__(256) void gemm3b_kernel(
    const float* __restrict__ x, const float* __restrict__ W, const float* __restrict__ bias,
    const float* __restrict__ a2, const float* __restrict__ s2,
    const float* __restrict__ a3, const float* __restrict__ s3,
    float* __restrict__ outp) {
  __shared__ float xs[kTileR][kC0P];
  __shared__ float wl[kC1][kC0P];
  const int tid = threadIdx.x;
  const int R0  = blockIdx.x * kTileR;
  const int G0  = R0 >> 5;
  for (int i = tid; i < kTileR * 16; i += 256) {
    const int r = i >> 4, cq = i & 15;
    float4 v = *(const float4*)&x[((size_t)(R0 + r)) * kC1 + cq * 4];
    const float4 av = *(const float4*)&a2[cq * 4];
    const float4 sv = *(const float4*)&s2[cq * 4];
    v.x = fmaxf(fmaf(av.x, v.x, sv.x), 0.0f);
    v.y = fmaxf(fmaf(av.y, v.y, sv.y), 0.0f);
    v.z = fmaxf(fmaf(av.z, v.z, sv.z), 0.0f);
    v.w = fmaxf(fmaf(av.w, v.w, sv.w), 0.0f);
    *(float4*)&xs[r][cq * 4] = v;
  }
  const int tr = tid & 15, tc = tid >> 4;
  for (int cp = 0; cp < 2; ++cp) {
    __syncthreads();
    for (int i = tid; i < kC1 * 16; i += 256) {
      const int o = i >> 4, cq = i & 15;
      *(float4*)&wl[o][cq * 4] = *(const float4*)&W[((size_t)(cp * 64 + o)) * kC1 + cq * 4];
    }
    __syncthreads();
    float acc[8][4];
    gemm_compute<kC1>(xs, wl, tr, tc, acc);
    float bb[4], av3[4], sv3[4];
#pragma unroll
    for (int j = 0; j < 4; ++j) {
      const int col = cp * 64 + tc * 4 + j;
      bb[j]  = bias[col];
      av3[j] = a3[col];
      sv3[j] = s3[col];
    }
    float mm[4][4];
#pragma unroll
    for (int i = 0; i < 8; ++i) {
      const int s4 = i >> 1;
#pragma unroll
      for (int j = 0; j < 4; ++j) {
        const float t = acc[i][j] + bb[j];
        const float v = fmaxf(fmaf(av3[j], t, sv3[j]), 0.0f);
        mm[s4][j] = (i & 1) ? fmaxf(mm[s4][j], v) : v;
      }
    }
#pragma unroll
    for (int off = 1; off < 16; off <<= 1)
#pragma unroll
      for (int s4 = 0; s4 < 4; ++s4)
#pragma unroll
        for (int j = 0; j < 4; ++j)
          mm[s4][j] = fmaxf(mm[s4][j], __shfl_xor(mm[s4][j], off, 64));
    if (tr == 0) {
#pragma unroll
      for (int s4 = 0; s4 < 4; ++s4) {
        *(float4*)&outp[(size_t)(G0 + s4) * kC3 + cp * 64 + tc * 4] =
            make_float4(mm[s4][0], mm[s4][1], mm[s4][2], mm[s4][3]);
      }
    }
  }
}

// ---------------- BN stats finalize (parallel) -------------------------------
// One block per channel; 256 threads reduce the 2048 per-block partials.
__global__ __launch_bounds__(256) void finalize_kernel(
    const float* __restrict__ psum, const float* __restrict__ psq,
    const float* __restrict__ g, const float* __restrict__ be,
    float* __restrict__ a, float* __restrict__ s, int nch) {
  __shared__ float red[2][4];
  const int c   = blockIdx.x;
  const int tid = threadIdx.x;
  const int lane = tid & 63, wid = tid >> 6;
  float sum = 0.f, sq = 0.f;
  for (int i = tid; i < kGemmBlocks; i += 256) {
    sum += psum[(size_t)i * nch + c];
    sq  += psq[(size_t)i * nch + c];
  }
#pragma unroll
  for (int off = 1; off < 64; off <<= 1) {
    sum += __shfl_xor(sum, off, 64);
    sq  += __shfl_xor(sq, off, 64);
  }
  if (lane == 0) { red[0][wid] = sum; red[1][wid] = sq; }
  __syncthreads();
  if (tid == 0) {
    const float tsum = red[0][0] + red[0][1] + red[0][2] + red[0][3];
    const float tsq  = red[1][0] + red[1][1] + red[1][2] + red[1][3];
    const float inv = 1.0f / (float)kRows;
    const float mu  = tsum * inv;
    const float var = tsq * inv - mu * mu;
    const float rs  = 1.0f / sqrtf(var + 1e-5f);
    const float av  = g[c] * rs;
    a[c] = av;
    s[c] = be[c] - av * mu;
  }
}

}  // namespace

extern "C" void kernel_launch(void* const* d_in, const int* in_sizes, int n_in,
                              void* d_out, int out_size, void* d_ws, size_t ws_size,
                              hipStream_t stream) {
  const float* xyz    = (const float*)d_in[0];
  const float* points = (const float*)d_in[1];
  const float* W0  = (const float*)d_in[2];
  const float* b0  = (const float*)d_in[3];
  const float* g0  = (const float*)d_in[4];
  const float* be0 = (const float*)d_in[5];
  const float* W1  = (const float*)d_in[6];
  const float* b1  = (const float*)d_in[7];
  const float* g1  = (const float*)d_in[8];
  const float* be1 = (const float*)d_in[9];
  const float* W2  = (const float*)d_in[10];
  const float* b2  = (const float*)d_in[11];
  const float* g2  = (const float*)d_in[12];
  const float* be2 = (const float*)d_in[13];

  float* out      = (float*)d_out;
  float* newxyz   = out;            // 8*1024*3 = 24576 floats
  float* newpts   = out + 24576;    // 8*1024*128

  char* wsb = (char*)d_ws;
  int*   gidx = (int*)wsb;                              // 1 MiB
  float* a1 = (float*)(wsb + (1u << 20));
  float* s1 = a1 + 128;
  float* a2 = s1 + 128;
  float* s2 = a2 + 128;
  float* a3 = s2 + 128;
  float* s3 = a3 + 128;
  float* psum = (float*)(wsb + 2u * (1u << 20));        // 1 MiB
  float* psq  = (float*)(wsb + 3u * (1u << 20));        // 1 MiB
  float* y1 = (float*)(wsb + 4u * (1u << 20));          // 64 MiB
  float* y2 = (float*)(wsb + 68u * (1u << 20));         // 64 MiB

  fps_kernel<<<kNB, 256, 0, stream>>>(xyz, newxyz);
  ballq_kernel<<<(kNB * kS) / 4, 256, 0, stream>>>(xyz, newxyz, gidx);
  gemm1_kernel<<<kGemmBlocks, 256, 0, stream>>>(xyz, points, newxyz, gidx, W0, b0, y1, psum, psq);
  finalize_kernel<<<64, 256, 0, stream>>>(psum, psq, g0, be0, a1, s1, 64);
  gemm2_kernel<<<kGemmBlocks, 256, 0, stream>>>(y1, W1, b1, a1, s1, y2, psum, psq);
  finalize_kernel<<<64, 256, 0, stream>>>(psum, psq, g1, be1, a2, s2, 64);
  gemm3a_kernel<<<kGemmBlocks, 256, 0, stream>>>(y2, W2, b2, a2, s2, psum, psq);
  finalize_kernel<<<128, 256, 0, stream>>>(psum, psq, g2, be2, a3, s3, 128);
  gemm3b_kernel<<<kGemmBlocks, 256, 0, stream>>>(y2, W2, b2, a2, s2, a3, s3, newpts);
}

// Round 15
// 960.563 us; speedup vs baseline: 1.0990x; 1.0990x over previous
//
#include <hip/hip_runtime.h>
#include <cstdint>
#include <cstddef>

namespace {

constexpr int kNB   = 8;
constexpr int kN    = 4096;
constexpr int kS    = 1024;   // NPOINT
constexpr int kK    = 32;     // NSAMPLE
constexpr int kInCh = 64;
constexpr int kC0   = 67;     // 3 + 64
constexpr int kC0P  = 68;     // padded (zero col at c'=3)
constexpr int kC1   = 64;
constexpr int kC3   = 128;
constexpr int kRows = kNB * kS * kK;  // 262144
constexpr int kTileR = 128;
constexpr int kGemmBlocks = kRows / kTileR;  // 2048

typedef float v2f __attribute__((ext_vector_type(2)));

// DPP max step: invalid source lanes fall back to `old` = x (identity for max).
template <int CTRL>
__device__ __forceinline__ float dpp_max(float x) {
  const int o = __builtin_amdgcn_update_dpp(
      __float_as_int(x), __float_as_int(x), CTRL, 0xf, 0xf, false);
  const float of = __int_as_float(o);
  return of > x ? of : x;
}

// ---------------- Farthest point sampling -----------------------------------
// FINAL structure: wave-count curve mapped (16w=0.73, 8w=0.66, 4w=0.75
// us/step) -> 8 waves x 8 pts/lane is the bracketed minimum (r12, fps 678us).
//  - one barrier/step; parity slots red[j&1][wid] WAR-safe.
//  - wave max via DPP row_shr/bcast + readlane(63); owner via ballot+ctz.
//  - red[p][wid] = u64 {value_bits:32, idx:32}; cross-wave: lane reads
//    red[p][lane&7], DPP row_shr 1/2/4 + readlane(7), ballot -> first lane
//    (<8) == first wave == min global index; index via readlane (SALU).
//  - centroid fetch: one uniform b128 broadcast sp[fi].
// Contiguous map i = 8*tid + t: min tie (t, lane, wave) == min global index ==
// numpy first-occurrence argmax. Distance arithmetic bit-identical to numpy:
// ((dx*dx+dy*dy)+dz*dz), RN ops, no FMA (packed v2f, contract off).
__global__ __launch_bounds__(512, 1) void fps_kernel(const float* __restrict__ xyz,
                                                     float* __restrict__ newxyz) {
  __shared__ float4 sp[kN];                     // 64 KiB
  __shared__ unsigned long long red[2][8];
  const int tid = threadIdx.x;
  const int b = blockIdx.x;
  const float* xb = xyz + (size_t)b * kN * 3;
  for (int i = tid; i < kN; i += 512) {
    sp[i] = make_float4(xb[i * 3 + 0], xb[i * 3 + 1], xb[i * 3 + 2], 0.0f);
  }
  __syncthreads();
  const int i0 = tid * 8;
  v2f pxv[4], pyv[4], pzv[4], dv[4];
#pragma unroll
  for (int h = 0; h < 4; ++h) {
    const float4 p0 = sp[i0 + 2 * h + 0];
    const float4 p1 = sp[i0 + 2 * h + 1];
    pxv[h] = (v2f){p0.x, p1.x};
    pyv[h] = (v2f){p0.y, p1.y};
    pzv[h] = (v2f){p0.z, p1.z};
    dv[h]  = (v2f){1e10f, 1e10f};
  }
  float4 c4 = sp[0];
  float cx = c4.x, cy = c4.y, cz = c4.z;
  float* ob = newxyz + (size_t)b * kS * 3;
  if (tid == 0) { ob[0] = cx; ob[1] = cy; ob[2] = cz; }
  const int lane = tid & 63;
  const int wid  = tid >> 6;
  for (int j = 1; j < kS; ++j) {
    // Packed distance update (RN, no FMA; per-element order identical to numpy).
    const float ncx = -cx, ncy = -cy, ncz = -cz;
    const v2f cxv = (v2f){ncx, ncx}, cyv = (v2f){ncy, ncy}, czv = (v2f){ncz, ncz};
#pragma unroll
    for (int h = 0; h < 4; ++h) {
#pragma clang fp contract(off)
      const v2f dx = pxv[h] + cxv;
      const v2f dy = pyv[h] + cyv;
      const v2f dz = pzv[h] + czv;
      const v2f d0 = ((dx * dx + dy * dy) + dz * dz);
      dv[h] = __builtin_elementwise_min(dv[h], d0);
    }
    // First-max over 8 via adjacent-pairing tree (left range < right range at
    // every level, so strict '>' keeps the first occurrence exactly).
    float lv[4]; int lt[4];
#pragma unroll
    for (int h = 0; h < 4; ++h) {
      const bool g = dv[h].y > dv[h].x;
      lv[h] = g ? dv[h].y : dv[h].x;
      lt[h] = 2 * h + (g ? 1 : 0);
    }
    const bool g01 = lv[1] > lv[0];
    const float v01 = g01 ? lv[1] : lv[0];
    const int   t01 = g01 ? lt[1] : lt[0];
    const bool g23 = lv[3] > lv[2];
    const float v23 = g23 ? lv[3] : lv[2];
    const int   t23 = g23 ? lt[3] : lt[2];
    const bool gf = v23 > v01;
    const float bv = gf ? v23 : v01;
    const int   bt = gf ? t23 : t01;
    // Wave max via DPP (pure VALU), broadcast from lane 63.
    float m = bv;
    m = dpp_max<0x111>(m);   // row_shr:1
    m = dpp_max<0x112>(m);   // row_shr:2
    m = dpp_max<0x114>(m);   // row_shr:4
    m = dpp_max<0x118>(m);   // row_shr:8
    m = dpp_max<0x142>(m);   // row_bcast:15
    m = dpp_max<0x143>(m);   // row_bcast:31
    const float mv = __int_as_float(__builtin_amdgcn_readlane(__float_as_int(m), 63));
    // First-occurrence: min tie lane == min global index (i = 8*tid + t).
    const unsigned long long msk = __ballot(bv == mv);
    const int owner = (int)__builtin_ctzll(msk);
    const int bto = __builtin_amdgcn_readlane(bt, owner);
    const int bidx = (wid * 64 + owner) * 8 + bto;
    const int p = j & 1;
    if (lane == 0) {
      red[p][wid] = ((unsigned long long)(unsigned int)__float_as_int(mv) << 32) |
                    (unsigned int)bidx;
    }
    __syncthreads();   // the ONLY barrier per step (parity slots are WAR-safe)
    // Cross-wave: one ds_read_b64 of red[p][lane&7]; DPP-max on the value (hi)
    // word over lanes 0..7; index via readlane from the first tying lane.
    const unsigned long long k64 = red[p][lane & 7];
    const float v2 = __int_as_float((int)(k64 >> 32));
    const int   li = (int)(unsigned int)(k64 & 0xffffffffull);
    float m2 = v2;
    m2 = dpp_max<0x111>(m2);
    m2 = dpp_max<0x112>(m2);
    m2 = dpp_max<0x114>(m2);
    const float mv2 = __int_as_float(__builtin_amdgcn_readlane(__float_as_int(m2), 7));
    const unsigned long long msk2 = __ballot(v2 == mv2);
    const int ow = (int)__builtin_ctzll(msk2);   // first lane (<8) == first wave
    const int fi = __builtin_amdgcn_readlane(li, ow);
    c4 = sp[fi];                                 // one b128 broadcast read
    cx = c4.x; cy = c4.y; cz = c4.z;
    if (tid == 0) { ob[j * 3 + 0] = cx; ob[j * 3 + 1] = cy; ob[j * 3 + 2] = cz; }
  }
}

// ---------------- Ball query -------------------------------------------------
// One wave per query point; first-32 in-radius indices in ascending order,
// padded with the first index. Distance uses the reference's expanded form and
// the compare is done in double (python float radius*radius).
__global__ __launch_bounds__(256) void ballq_kernel(const float* __restrict__ xyz,
                                                    const float* __restrict__ newxyz,
                                                    int* __restrict__ gidx) {
  const int tid  = threadIdx.x;
  const int lane = tid & 63;
  const int gq   = blockIdx.x * 4 + (tid >> 6);
  const int b    = gq >> 10;
  const float* xb = xyz + (size_t)b * kN * 3;
  const float qx = newxyz[gq * 3 + 0];
  const float qy = newxyz[gq * 3 + 1];
  const float qz = newxyz[gq * 3 + 2];
  const float s2 = __fadd_rn(__fadd_rn(__fmul_rn(qx, qx), __fmul_rn(qy, qy)),
                             __fmul_rn(qz, qz));
  const double r2 = 0.2 * 0.2;
  int taken = 0;
  int first = 0;
  bool hasfirst = false;
  int* g = gidx + (size_t)gq * kK;
  for (int base = 0; base < kN; base += 64) {
    const int n = base + lane;
    const float fx = xb[n * 3 + 0], fy = xb[n * 3 + 1], fz = xb[n * 3 + 2];
    const float p2 = __fadd_rn(__fadd_rn(__fmul_rn(fx, fx), __fmul_rn(fy, fy)),
                               __fmul_rn(fz, fz));
    const float dt = __fadd_rn(__fadd_rn(__fmul_rn(qx, fx), __fmul_rn(qy, fy)),
                               __fmul_rn(qz, fz));
    const float d = __fadd_rn(__fadd_rn(__fmul_rn(-2.0f, dt), s2), p2);
    const bool in = !((double)d > r2);
    const unsigned long long m = __ballot(in);
    if (!hasfirst && m != 0ull) { first = base + __builtin_ctzll(m); hasfirst = true; }
    if (in) {
      const int pos = taken + (int)__popcll(m & ((1ull << lane) - 1ull));
      if (pos < kK) g[pos] = n;
    }
    taken += (int)__popcll(m);
    if (taken >= kK) break;
  }
  for (int p = taken + lane; p < kK; p += 64) g[p] = first;
}

// ---------------- GEMM core (shared pattern) ---------------------------------
// Block: 256 threads, tile 128 rows x 64 cols. Thread (tr = tid&15, tc = tid>>4)
// computes rows {tr+16i} x cols {tc*4+j}, acc[8][4].

template <int KDIM>
__device__ __forceinline__ void gemm_compute(const float xs[kTileR][kC0P],
                                             const float wl[kC1][kC0P],
                                             int tr, int tc, float acc[8][4]) {
#pragma unroll
  for (int i = 0; i < 8; ++i)
#pragma unroll
    for (int j = 0; j < 4; ++j) acc[i][j] = 0.0f;
#pragma unroll 4
  for (int c = 0; c < KDIM; c += 4) {
    const float4 wv0 = *(const float4*)&wl[tc * 4 + 0][c];
    const float4 wv1 = *(const float4*)&wl[tc * 4 + 1][c];
    const float4 wv2 = *(const float4*)&wl[tc * 4 + 2][c];
    const float4 wv3 = *(const float4*)&wl[tc * 4 + 3][c];
#pragma unroll
    for (int i = 0; i < 8; ++i) {
      const float4 xv = *(const float4*)&xs[tr + 16 * i][c];
      acc[i][0] = fmaf(xv.x, wv0.x, acc[i][0]);
      acc[i][0] = fmaf(xv.y, wv0.y, acc[i][0]);
      acc[i][0] = fmaf(xv.z, wv0.z, acc[i][0]);
      acc[i][0] = fmaf(xv.w, wv0.w, acc[i][0]);
      acc[i][1] = fmaf(xv.x, wv1.x, acc[i][1]);
      acc[i][1] = fmaf(xv.y, wv1.y, acc[i][1]);
      acc[i][1] = fmaf(xv.z, wv1.z, acc[i][1]);
      acc[i][1] = fmaf(xv.w, wv1.w, acc[i][1]);
      acc[i][2] = fmaf(xv.x, wv2.x, acc[i][2]);
      acc[i][2] = fmaf(xv.y, wv2.y, acc[i][2]);
      acc[i][2] = fmaf(xv.z, wv2.z, acc[i][2]);
      acc[i][2] = fmaf(xv.w, wv2.w, acc[i][2]);
      acc[i][3] = fmaf(xv.x, wv3.x, acc[i][3]);
      acc[i][3] = fmaf(xv.y, wv3.y, acc[i][3]);
      acc[i][3] = fmaf(xv.z, wv3.z, acc[i][3]);
      acc[i][3] = fmaf(xv.w, wv3.w, acc[i][3]);
    }
  }
}

// Epilogue: add bias, write y, and per-channel {sum, sumsq} partials.
__device__ __forceinline__ void gemm_store_stats(float acc[8][4], const float* __restrict__ bias,
                                                 float* __restrict__ y,
                                                 float* __restrict__ psum, float* __restrict__ psq,
                                                 int R0, int tr, int tc, int bid) {
  float bb[4];
#pragma unroll
  for (int j = 0; j < 4; ++j) bb[j] = bias[tc * 4 + j];
  float sum[4] = {0, 0, 0, 0}, sq[4] = {0, 0, 0, 0};
#pragma unroll
  for (int i = 0; i < 8; ++i) {
    float v[4];
#pragma unroll
    for (int j = 0; j < 4; ++j) {
      const float t = acc[i][j] + bb[j];
      v[j] = t;
      sum[j] += t;
      sq[j] = fmaf(t, t, sq[j]);
    }
    *(float4*)&y[((size_t)(R0 + tr + 16 * i)) * kC1 + tc * 4] =
        make_float4(v[0], v[1], v[2], v[3]);
  }
#pragma unroll
  for (int off = 1; off < 16; off <<= 1) {
#pragma unroll
    for (int j = 0; j < 4; ++j) {
      sum[j] += __shfl_xor(sum[j], off, 64);
      sq[j]  += __shfl_xor(sq[j], off, 64);
    }
  }
  if (tr == 0) {
    *(float4*)&psum[(size_t)bid * kC1 + tc * 4] = make_float4(sum[0], sum[1], sum[2], sum[3]);
    *(float4*)&psq[(size_t)bid * kC1 + tc * 4]  = make_float4(sq[0], sq[1], sq[2], sq[3]);
  }
}

// ---------------- Layer 1: fused gather + GEMM(K=67->68, N=64) ---------------
__global__ __launch_bounds__(256) void gemm1_kernel(
    const float* __restrict__ xyz, const float* __restrict__ points,
    const float* __restrict__ newxyz, const int* __restrict__ gidx,
    const float* __restrict__ W, const float* __restrict__ bias,
    float* __restrict__ y, float* __restrict__ psum, float* __restrict__ psq) {
  __shared__ float xs[kTileR][kC0P];
  __shared__ float wl[kC1][kC0P];
  __shared__ int   gl[kTileR];
  __shared__ float nx[4][3];
  const int tid = threadIdx.x;
  const int R0  = blockIdx.x * kTileR;
  const int b   = R0 >> 15;          // 32768 rows per batch
  const int G0  = R0 >> 5;           // global group id base (4 groups per tile)
  if (tid < kTileR) gl[tid] = gidx[R0 + tid];
  if (tid >= 128 && tid < 140) {
    const int q = (tid - 128) / 3, c = (tid - 128) % 3;
    nx[q][c] = newxyz[(size_t)(G0 + q) * 3 + c];
  }
  // Stage W reordered: c'=0..2 -> W[:,0..2], c'=3 -> 0, c'>=4 -> W[:,c'-1]
  for (int i = tid; i < kC1 * kC0P; i += 256) {
    const int o = i / kC0P, c = i % kC0P;
    float v;
    if (c < 3)       v = W[o * kC0 + c];
    else if (c == 3) v = 0.0f;
    else             v = W[o * kC0 + (c - 1)];
    wl[o][c] = v;
  }
  __syncthreads();
  // Gather-stage xs: [dx,dy,dz,0, p0..p63]
  for (int i = tid; i < kTileR * 17; i += 256) {
    const int r = i / 17, q = i % 17;
    const int n = gl[r];
    if (q == 0) {
      const float* xp = xyz + ((size_t)(b * kN + n)) * 3;
      const int sq4 = r >> 5;
      xs[r][0] = __fsub_rn(xp[0], nx[sq4][0]);
      xs[r][1] = __fsub_rn(xp[1], nx[sq4][1]);
      xs[r][2] = __fsub_rn(xp[2], nx[sq4][2]);
      xs[r][3] = 0.0f;
    } else {
      const float4 p = *(const float4*)(points + ((size_t)(b * kN + n)) * kInCh + (q - 1) * 4);
      *(float4*)&xs[r][q * 4] = p;
    }
  }
  __syncthreads();
  const int tr = tid & 15, tc = tid >> 4;
  float acc[8][4];
  gemm_compute<kC0P>(xs, wl, tr, tc, acc);
  gemm_store_stats(acc, bias, y, psum, psq, R0, tr, tc, blockIdx.x);
}

// ---------------- Layer 2: GEMM(K=64, N=64), BN1+ReLU fused on input --------
__global__ __launch_bounds__(256) void gemm2_kernel(
    const float* __restrict__ x, const float* __restrict__ W, const float* __restrict__ bias,
    const float* __restrict__ a, const float* __restrict__ sft,
    float* __restrict__ y, float* __restrict__ psum, float* __restrict__ psq) {
  __shared__ float xs[kTileR][kC0P];
  __shared__ float wl[kC1][kC0P];
  const int tid = threadIdx.x;
  const int R0  = blockIdx.x * kTileR;
  for (int i = tid; i < kTileR * 16; i += 256) {
    const int r = i >> 4, cq = i & 15;
    float4 v = *(const float4*)&x[((size_t)(R0 + r)) * kC1 + cq * 4];
    const float4 av = *(const float4*)&a[cq * 4];
    const float4 sv = *(const float4*)&sft[cq * 4];
    v.x = fmaxf(fmaf(av.x, v.x, sv.x), 0.0f);
    v.y = fmaxf(fmaf(av.y, v.y, sv.y), 0.0f);
    v.z = fmaxf(fmaf(av.z, v.z, sv.z), 0.0f);
    v.w = fmaxf(fmaf(av.w, v.w, sv.w), 0.0f);
    *(float4*)&xs[r][cq * 4] = v;
  }
  for (int i = tid; i < kC1 * 16; i += 256) {
    const int o = i >> 4, cq = i & 15;
    *(float4*)&wl[o][cq * 4] = *(const float4*)&W[(size_t)o * kC1 + cq * 4];
  }
  __syncthreads();
  const int tr = tid & 15, tc = tid >> 4;
  float acc[8][4];
  gemm_compute<kC1>(xs, wl, tr, tc, acc);
  gemm_store_stats(acc, bias, y, psum, psq, R0, tr, tc, blockIdx.x);
}

// ---------------- Layer 3 pass A: stats only (no y3 store) -------------------
__global__ __launch_bounds__(256) void gemm3a_kernel(
    const float* __restrict__ x, const float* __restrict__ W, const float* __restrict__ bias,
    const float* __restrict__ a, const float* __restrict__ sft,
    float* __restrict__ psum, float* __restrict__ psq) {
  __shared__ float xs[kTileR][kC0P];
  __shared__ float wl[kC1][kC0P];
  const int tid = threadIdx.x;
  const int R0  = blockIdx.x * kTileR;
  for (int i = tid; i < kTileR * 16; i += 256) {
    const int r = i >> 4, cq = i & 15;
    float4 v = *(const float4*)&x[((size_t)(R0 + r)) * kC1 + cq * 4];
    const float4 av = *(const float4*)&a[cq * 4];
    const float4 sv = *(const float4*)&sft[cq * 4];
    v.x = fmaxf(fmaf(av.x, v.x, sv.x), 0.0f);
    v.y = fmaxf(fmaf(av.y, v.y, sv.y), 0.0f);
    v.z = fmaxf(fmaf(av.z, v.z, sv.z), 0.0f);
    v.w = fmaxf(fmaf(av.w, v.w, sv.w), 0.0f);
    *(float4*)&xs[r][cq * 4] = v;
  }
  const int tr = tid & 15, tc = tid >> 4;
  for (int cp = 0; cp < 2; ++cp) {
    __syncthreads();
    for (int i = tid; i < kC1 * 16; i += 256) {
      const int o = i >> 4, cq = i & 15;
      *(float4*)&wl[o][cq * 4] = *(const float4*)&W[((size_t)(cp * 64 + o)) * kC1 + cq * 4];
    }
    __syncthreads();
    float acc[8][4];
    gemm_compute<kC1>(xs, wl, tr, tc, acc);
    float bb[4];
#pragma unroll
    for (int j = 0; j < 4; ++j) bb[j] = bias[cp * 64 + tc * 4 + j];
    float sum[4] = {0, 0, 0, 0}, sq[4] = {0, 0, 0, 0};
#pragma unroll
    for (int i = 0; i < 8; ++i)
#pragma unroll
      for (int j = 0; j < 4; ++j) {
        const float t = acc[i][j] + bb[j];
        sum[j] += t;
        sq[j] = fmaf(t, t, sq[j]);
      }
#pragma unroll
    for (int off = 1; off < 16; off <<= 1) {
#pragma unroll
      for (int j = 0; j < 4; ++j) {
        sum[j] += __shfl_xor(sum[j], off, 64);
        sq[j]  += __shfl_xor(sq[j], off, 64);
      }
    }
    if (tr == 0) {
      *(float4*)&psum[(size_t)blockIdx.x * kC3 + cp * 64 + tc * 4] =
          make_float4(sum[0], sum[1], sum[2], sum[3]);
      *(float4*)&psq[(size_t)blockIdx.x * kC3 + cp * 64 + tc * 4] =
          make_float4(sq[0], sq[1], sq[2], sq[3]);
    }
  }
}

// ---------------- Layer 3 pass B: recompute + BN3 + ReLU + max over k -------
__global__ __launch_bounds__(256) void gemm3b_kernel(
    const float* __restrict__ x, const float* __restrict__ W, const float* __restrict__ bias,
    const float* __restrict__ a2, const float* __restrict__ s2,
    const float* __restrict__ a3, const float* __restrict__ s3,
    float* __restrict__ outp) {
  __shared__ float xs[kTileR][kC0P];
  __shared__ float wl[kC1][kC0P];
  const int tid = threadIdx.x;
  const int R0  = blockIdx.x * kTileR;
  const int G0  = R0 >> 5;
  for (int i = tid; i < kTileR * 16; i += 256) {
    const int r = i >> 4, cq = i & 15;
    float4 v = *(const float4*)&x[((size_t)(R0 + r)) * kC1 + cq * 4];
    const float4 av = *(const float4*)&a2[cq * 4];
    const float4 sv = *(const float4*)&s2[cq * 4];
    v.x = fmaxf(fmaf(av.x, v.x, sv.x), 0.0f);
    v.y = fmaxf(fmaf(av.y, v.y, sv.y), 0.0f);
    v.z = fmaxf(fmaf(av.z, v.z, sv.z), 0.0f);
    v.w = fmaxf(fmaf(av.w, v.w, sv.w), 0.0f);
    *(float4*)&xs[r][cq * 4] = v;
  }
  const int tr = tid & 15, tc = tid >> 4;
  for (int cp = 0; cp < 2; ++cp) {
    __syncthreads();
    for (int i = tid; i < kC1 * 16; i += 256) {
      const int o = i >> 4, cq = i & 15;
      *(float4*)&wl[o][cq * 4] = *(const float4*)&W[((size_t)(cp * 64 + o)) * kC1 + cq * 4];
    }
    __syncthreads();
    float acc[8][4];
    gemm_compute<kC1>(xs, wl, tr, tc, acc);
    float bb[4], av3[4], sv3[4];
#pragma unroll
    for (int j = 0; j < 4; ++j) {
      const int col = cp * 64 + tc * 4 + j;
      bb[j]  = bias[col];
      av3[j] = a3[col];
      sv3[j] = s3[col];
    }
    float mm[4][4];
#pragma unroll
    for (int i = 0; i < 8; ++i) {
      const int s4 = i >> 1;
#pragma unroll
      for (int j = 0; j < 4; ++j) {
        const float t = acc[i][j] + bb[j];
        const float v = fmaxf(fmaf(av3[j], t, sv3[j]), 0.0f);
        mm[s4][j] = (i & 1) ? fmaxf(mm[s4][j], v) : v;
      }
    }
#pragma unroll
    for (int off = 1; off < 16; off <<= 1)
#pragma unroll
      for (int s4 = 0; s4 < 4; ++s4)
#pragma unroll
        for (int j = 0; j < 4; ++j)
          mm[s4][j] = fmaxf(mm[s4][j], __shfl_xor(mm[s4][j], off, 64));
    if (tr == 0) {
#pragma unroll
      for (int s4 = 0; s4 < 4; ++s4) {
        *(float4*)&outp[(size_t)(G0 + s4) * kC3 + cp * 64 + tc * 4] =
            make_float4(mm[s4][0], mm[s4][1], mm[s4][2], mm[s4][3]);
      }
    }
  }
}

// ---------------- BN stats finalize (parallel) -------------------------------
// One block per channel; 256 threads reduce the 2048 per-block partials.
__global__ __launch_bounds__(256) void finalize_kernel(
    const float* __restrict__ psum, const float* __restrict__ psq,
    const float* __restrict__ g, const float* __restrict__ be,
    float* __restrict__ a, float* __restrict__ s, int nch) {
  __shared__ float red[2][4];
  const int c   = blockIdx.x;
  const int tid = threadIdx.x;
  const int lane = tid & 63, wid = tid >> 6;
  float sum = 0.f, sq = 0.f;
  for (int i = tid; i < kGemmBlocks; i += 256) {
    sum += psum[(size_t)i * nch + c];
    sq  += psq[(size_t)i * nch + c];
  }
#pragma unroll
  for (int off = 1; off < 64; off <<= 1) {
    sum += __shfl_xor(sum, off, 64);
    sq  += __shfl_xor(sq, off, 64);
  }
  if (lane == 0) { red[0][wid] = sum; red[1][wid] = sq; }
  __syncthreads();
  if (tid == 0) {
    const float tsum = red[0][0] + red[0][1] + red[0][2] + red[0][3];
    const float tsq  = red[1][0] + red[1][1] + red[1][2] + red[1][3];
    const float inv = 1.0f / (float)kRows;
    const float mu  = tsum * inv;
    const float var = tsq * inv - mu * mu;
    const float rs  = 1.0f / sqrtf(var + 1e-5f);
    const float av  = g[c] * rs;
    a[c] = av;
    s[c] = be[c] - av * mu;
  }
}

}  // namespace

extern "C" void kernel_launch(void* const* d_in, const int* in_sizes, int n_in,
                              void* d_out, int out_size, void* d_ws, size_t ws_size,
                              hipStream_t stream) {
  const float* xyz    = (const float*)d_in[0];
  const float* points = (const float*)d_in[1];
  const float* W0  = (const float*)d_in[2];
  const float* b0  = (const float*)d_in[3];
  const float* g0  = (const float*)d_in[4];
  const float* be0 = (const float*)d_in[5];
  const float* W1  = (const float*)d_in[6];
  const float* b1  = (const float*)d_in[7];
  const float* g1  = (const float*)d_in[8];
  const float* be1 = (const float*)d_in[9];
  const float* W2  = (const float*)d_in[10];
  const float* b2  = (const float*)d_in[11];
  const float* g2  = (const float*)d_in[12];
  const float* be2 = (const float*)d_in[13];

  float* out      = (float*)d_out;
  float* newxyz   = out;            // 8*1024*3 = 24576 floats
  float* newpts   = out + 24576;    // 8*1024*128

  char* wsb = (char*)d_ws;
  int*   gidx = (int*)wsb;                              // 1 MiB
  float* a1 = (float*)(wsb + (1u << 20));
  float* s1 = a1 + 128;
  float* a2 = s1 + 128;
  float* s2 = a2 + 128;
  float* a3 = s2 + 128;
  float* s3 = a3 + 128;
  float* psum = (float*)(wsb + 2u * (1u << 20));        // 1 MiB
  float* psq  = (float*)(wsb + 3u * (1u << 20));        // 1 MiB
  float* y1 = (float*)(wsb + 4u * (1u << 20));          // 64 MiB
  float* y2 = (float*)(wsb + 68u * (1u << 20));         // 64 MiB

  fps_kernel<<<kNB, 512, 0, stream>>>(xyz, newxyz);
  ballq_kernel<<<(kNB * kS) / 4, 256, 0, stream>>>(xyz, newxyz, gidx);
  gemm1_kernel<<<kGemmBlocks, 256, 0, stream>>>(xyz, points, newxyz, gidx, W0, b0, y1, psum, psq);
  finalize_kernel<<<64, 256, 0, stream>>>(psum, psq, g0, be0, a1, s1, 64);
  gemm2_kernel<<<kGemmBlocks, 256, 0, stream>>>(y1, W1, b1, a1, s1, y2, psum, psq);
  finalize_kernel<<<64, 256, 0, stream>>>(psum, psq, g1, be1, a2, s2, 64);
  gemm3a_kernel<<<kGemmBlocks, 256, 0, stream>>>(y2, W2, b2, a2, s2, psum, psq);
  finalize_kernel<<<128, 256, 0, stream>>>(psum, psq, g2, be2, a3, s3, 128);
  gemm3b_kernel<<<kGemmBlocks, 256, 0, stream>>>(y2, W2, b2, a2, s2, a3, s3, newpts);
}